// Round 1
// baseline (1499.028 us; speedup 1.0000x reference)
//
#include <hip/hip_runtime.h>

#define N_NODES 100000
#define N_EDGES 3200000
#define F_IN 128
#define HID 16

// ---------------- degree ----------------
__global__ __launch_bounds__(256) void k_deg(const int* __restrict__ dst,
                                             int* __restrict__ deg, int E) {
    int e = blockIdx.x * 256 + threadIdx.x;
    if (e < E) atomicAdd(&deg[dst[e]], 1);
}

__global__ __launch_bounds__(256) void k_dinv(const int* __restrict__ deg,
                                              float* __restrict__ dinv, int N) {
    int i = blockIdx.x * 256 + threadIdx.x;
    if (i < N) dinv[i] = rsqrtf((float)(deg[i] + 1));  // +1 self-loop
}

// ---------------- GEMM1: g = (x @ W1) * dinv,  K=128 ----------------
__global__ __launch_bounds__(256) void k_gemm1(const float* __restrict__ x,
                                               const float* __restrict__ W1,
                                               const float* __restrict__ dinv,
                                               float* __restrict__ g, int N) {
    __shared__ float w[F_IN * HID];
    for (int t = threadIdx.x; t < F_IN * HID; t += 256) w[t] = W1[t];
    __syncthreads();
    int i = blockIdx.x * 256 + threadIdx.x;
    if (i >= N) return;
    float acc[HID];
#pragma unroll
    for (int n = 0; n < HID; n++) acc[n] = 0.f;
    const float4* xr = (const float4*)(x + (size_t)i * F_IN);
#pragma unroll 4
    for (int k4 = 0; k4 < F_IN / 4; k4++) {
        float4 xv = xr[k4];
        int k = k4 * 4;
#pragma unroll
        for (int n = 0; n < HID; n++) {
            acc[n] += xv.x * w[(k + 0) * HID + n] + xv.y * w[(k + 1) * HID + n] +
                      xv.z * w[(k + 2) * HID + n] + xv.w * w[(k + 3) * HID + n];
        }
    }
    float dv = dinv[i];
    float4* go = (float4*)(g + (size_t)i * HID);
#pragma unroll
    for (int n4 = 0; n4 < 4; n4++) {
        float4 o;
        o.x = acc[n4 * 4 + 0] * dv;
        o.y = acc[n4 * 4 + 1] * dv;
        o.z = acc[n4 * 4 + 2] * dv;
        o.w = acc[n4 * 4 + 3] * dv;
        go[n4] = o;
    }
}

// ---------------- scatter: acc[dst] += g[src] (16 f32 per edge) ----------------
__global__ __launch_bounds__(256) void k_scatter(const int* __restrict__ src,
                                                 const int* __restrict__ dst,
                                                 const float* __restrict__ g,
                                                 float* __restrict__ acc, int E) {
    int t = blockIdx.x * 256 + threadIdx.x;
    int e = t >> 2, j = t & 3;
    if (e >= E) return;
    int s = src[e], d = dst[e];
    float4 v = ((const float4*)(g + (size_t)s * HID))[j];
    float* a = acc + (size_t)d * HID + j * 4;
    atomicAdd(a + 0, v.x);
    atomicAdd(a + 1, v.y);
    atomicAdd(a + 2, v.z);
    atomicAdd(a + 3, v.w);
}

// ---------------- finish: h = [relu](dinv*(acc+g) + b) ----------------
__global__ __launch_bounds__(256) void k_finish(const float* __restrict__ acc,
                                                const float* __restrict__ g,
                                                const float* __restrict__ dinv,
                                                const float* __restrict__ b,
                                                float* __restrict__ h, int N, int do_relu) {
    int t = blockIdx.x * 256 + threadIdx.x;
    int i = t >> 2, j = t & 3;
    if (i >= N) return;
    float dv = dinv[i];
    float4 a = ((const float4*)(acc + (size_t)i * HID))[j];
    float4 gg = ((const float4*)(g + (size_t)i * HID))[j];
    float4 bb = ((const float4*)b)[j];
    float4 o;
    o.x = dv * (a.x + gg.x) + bb.x;
    o.y = dv * (a.y + gg.y) + bb.y;
    o.z = dv * (a.z + gg.z) + bb.z;
    o.w = dv * (a.w + gg.w) + bb.w;
    if (do_relu) {
        o.x = fmaxf(o.x, 0.f);
        o.y = fmaxf(o.y, 0.f);
        o.z = fmaxf(o.z, 0.f);
        o.w = fmaxf(o.w, 0.f);
    }
    ((float4*)(h + (size_t)i * HID))[j] = o;
}

// ---------------- GEMM2: g = (h1 @ W2) * dinv,  K=16 ----------------
__global__ __launch_bounds__(256) void k_gemm2(const float* __restrict__ h1,
                                               const float* __restrict__ W2,
                                               const float* __restrict__ dinv,
                                               float* __restrict__ g, int N) {
    __shared__ float w[HID * HID];
    if (threadIdx.x < HID * HID) w[threadIdx.x] = W2[threadIdx.x];
    __syncthreads();
    int i = blockIdx.x * 256 + threadIdx.x;
    if (i >= N) return;
    float hv[HID];
    const float4* hr = (const float4*)(h1 + (size_t)i * HID);
#pragma unroll
    for (int j = 0; j < 4; j++) {
        float4 v = hr[j];
        hv[j * 4 + 0] = v.x;
        hv[j * 4 + 1] = v.y;
        hv[j * 4 + 2] = v.z;
        hv[j * 4 + 3] = v.w;
    }
    float dv = dinv[i];
    float4* go = (float4*)(g + (size_t)i * HID);
#pragma unroll
    for (int n4 = 0; n4 < 4; n4++) {
        float4 o;
        float s0 = 0.f, s1 = 0.f, s2 = 0.f, s3 = 0.f;
#pragma unroll
        for (int k = 0; k < HID; k++) {
            s0 += hv[k] * w[k * HID + n4 * 4 + 0];
            s1 += hv[k] * w[k * HID + n4 * 4 + 1];
            s2 += hv[k] * w[k * HID + n4 * 4 + 2];
            s3 += hv[k] * w[k * HID + n4 * 4 + 3];
        }
        o.x = s0 * dv;
        o.y = s1 * dv;
        o.z = s2 * dv;
        o.w = s3 * dv;
        go[n4] = o;
    }
}

// ---------------- edge scoring ----------------
__global__ __launch_bounds__(256) void k_edge(const int* __restrict__ src,
                                              const int* __restrict__ dst,
                                              const float* __restrict__ h2,
                                              const float* __restrict__ Wf,
                                              const float* __restrict__ bf,
                                              float* __restrict__ pred, int E) {
    __shared__ float wf[33];
    if (threadIdx.x < 33) wf[threadIdx.x] = (threadIdx.x < 32) ? Wf[threadIdx.x] : bf[0];
    __syncthreads();
    int e = blockIdx.x * 256 + threadIdx.x;
    if (e >= E) return;
    int s = src[e], d = dst[e];
    const float4* hs = (const float4*)(h2 + (size_t)s * HID);
    const float4* hd = (const float4*)(h2 + (size_t)d * HID);
    float sum = wf[32];
#pragma unroll
    for (int j = 0; j < 4; j++) {
        float4 v = hs[j];
        sum += v.x * wf[j * 4 + 0] + v.y * wf[j * 4 + 1] + v.z * wf[j * 4 + 2] + v.w * wf[j * 4 + 3];
    }
#pragma unroll
    for (int j = 0; j < 4; j++) {
        float4 v = hd[j];
        sum += v.x * wf[16 + j * 4 + 0] + v.y * wf[16 + j * 4 + 1] + v.z * wf[16 + j * 4 + 2] +
               v.w * wf[16 + j * 4 + 3];
    }
    pred[e] = sum;
}

extern "C" void kernel_launch(void* const* d_in, const int* in_sizes, int n_in,
                              void* d_out, int out_size, void* d_ws, size_t ws_size,
                              hipStream_t stream) {
    const float* x  = (const float*)d_in[0];
    const int*   ei = (const int*)d_in[1];
    const float* W1 = (const float*)d_in[2];
    const float* b1 = (const float*)d_in[3];
    const float* W2 = (const float*)d_in[4];
    const float* b2 = (const float*)d_in[5];
    const float* Wf = (const float*)d_in[6];
    const float* bf = (const float*)d_in[7];
    float* pred = (float*)d_out;

    const int N = N_NODES, E = N_EDGES;
    const int* src = ei;
    const int* dst = ei + E;

    // workspace layout (bytes): all 256B-aligned
    char* w = (char*)d_ws;
    int*   deg  = (int*)(w + 0x0);        // 400000 B
    float* dinv = (float*)(w + 0x80000);  // 400000 B
    float* g    = (float*)(w + 0x100000); // 6.4 MB
    float* acc  = (float*)(w + 0x780000); // 6.4 MB
    float* h1   = (float*)(w + 0xE00000); // 6.4 MB
    float* h2   = (float*)(w + 0x1480000);// 6.4 MB  (total ~27 MB)

    const int B = 256;
    int gE  = (E + B - 1) / B;          // 12500
    int gE4 = (4 * E + B - 1) / B;      // 50000
    int gN  = (N + B - 1) / B;          // 391
    int gN4 = (4 * N + B - 1) / B;      // 1563

    // degree + dinv
    hipMemsetAsync(deg, 0, (size_t)N * 4, stream);
    k_deg<<<gE, B, 0, stream>>>(dst, deg, E);
    k_dinv<<<gN, B, 0, stream>>>(deg, dinv, N);

    // conv1
    k_gemm1<<<gN, B, 0, stream>>>(x, W1, dinv, g, N);
    hipMemsetAsync(acc, 0, (size_t)N * HID * 4, stream);
    k_scatter<<<gE4, B, 0, stream>>>(src, dst, g, acc, E);
    k_finish<<<gN4, B, 0, stream>>>(acc, g, dinv, b1, h1, N, 1);

    // conv2
    k_gemm2<<<gN, B, 0, stream>>>(h1, W2, dinv, g, N);
    hipMemsetAsync(acc, 0, (size_t)N * HID * 4, stream);
    k_scatter<<<gE4, B, 0, stream>>>(src, dst, g, acc, E);
    k_finish<<<gN4, B, 0, stream>>>(acc, g, dinv, b2, h2, N, 0);

    // edge scoring
    k_edge<<<gE, B, 0, stream>>>(src, dst, h2, Wf, bf, pred, E);
}

// Round 2
// 600.043 us; speedup vs baseline: 2.4982x; 2.4982x over previous
//
#include <hip/hip_runtime.h>

#define N_NODES 100000
#define N_EDGES 3200000
#define F_IN 128
#define HID 16

// ---------------- degree histogram (real in-edges, no self-loop) ----------------
__global__ __launch_bounds__(256) void k_deg(const int* __restrict__ dst,
                                             int* __restrict__ deg, int E) {
    int e = blockIdx.x * 256 + threadIdx.x;
    if (e < E) atomicAdd(&deg[dst[e]], 1);
}

__global__ __launch_bounds__(256) void k_dinv(const int* __restrict__ deg,
                                              float* __restrict__ dinv, int N) {
    int i = blockIdx.x * 256 + threadIdx.x;
    if (i < N) dinv[i] = rsqrtf((float)(deg[i] + 1));  // +1 self-loop
}

// ---------------- exclusive scan of deg -> off (3-phase) ----------------
__global__ __launch_bounds__(256) void k_scan1(const int* __restrict__ deg,
                                               int* __restrict__ off,
                                               int* __restrict__ bsum, int N) {
    __shared__ int s[256];
    int t = threadIdx.x;
    int i = blockIdx.x * 256 + t;
    int v = (i < N) ? deg[i] : 0;
    s[t] = v;
    __syncthreads();
#pragma unroll
    for (int o = 1; o < 256; o <<= 1) {
        int x = (t >= o) ? s[t - o] : 0;
        __syncthreads();
        s[t] += x;
        __syncthreads();
    }
    if (i < N) off[i] = s[t] - v;  // exclusive
    if (t == 255) bsum[blockIdx.x] = s[255];
}

__global__ __launch_bounds__(512) void k_scan2(int* __restrict__ bsum, int nb) {
    __shared__ int s[512];
    int t = threadIdx.x;
    int v = (t < nb) ? bsum[t] : 0;
    s[t] = v;
    __syncthreads();
#pragma unroll
    for (int o = 1; o < 512; o <<= 1) {
        int x = (t >= o) ? s[t - o] : 0;
        __syncthreads();
        s[t] += x;
        __syncthreads();
    }
    if (t < nb) bsum[t] = s[t] - v;  // exclusive block offsets
}

__global__ __launch_bounds__(256) void k_scan3(int* __restrict__ off,
                                               const int* __restrict__ bsum,
                                               int* __restrict__ cursor, int N, int E) {
    int i = blockIdx.x * 256 + threadIdx.x;
    if (i < N) {
        int v = off[i] + bsum[blockIdx.x];
        off[i] = v;
        cursor[i] = v;
    }
    if (i == 0) off[N] = E;
}

// ---------------- CSR fill: ebuf[pos] = src, bucketed by dst ----------------
__global__ __launch_bounds__(256) void k_fill(const int* __restrict__ src,
                                              const int* __restrict__ dst,
                                              int* __restrict__ cursor,
                                              int* __restrict__ ebuf, int E) {
    int e = blockIdx.x * 256 + threadIdx.x;
    if (e < E) {
        int p = atomicAdd(&cursor[dst[e]], 1);
        ebuf[p] = src[e];
    }
}

// ---------------- GEMM1: g = (x @ W1) * dinv,  K=128 ----------------
__global__ __launch_bounds__(256) void k_gemm1(const float* __restrict__ x,
                                               const float* __restrict__ W1,
                                               const float* __restrict__ dinv,
                                               float* __restrict__ g, int N) {
    __shared__ float w[F_IN * HID];
    for (int t = threadIdx.x; t < F_IN * HID; t += 256) w[t] = W1[t];
    __syncthreads();
    int i = blockIdx.x * 256 + threadIdx.x;
    if (i >= N) return;
    float acc[HID];
#pragma unroll
    for (int n = 0; n < HID; n++) acc[n] = 0.f;
    const float4* xr = (const float4*)(x + (size_t)i * F_IN);
#pragma unroll 4
    for (int k4 = 0; k4 < F_IN / 4; k4++) {
        float4 xv = xr[k4];
        int k = k4 * 4;
#pragma unroll
        for (int n = 0; n < HID; n++) {
            acc[n] += xv.x * w[(k + 0) * HID + n] + xv.y * w[(k + 1) * HID + n] +
                      xv.z * w[(k + 2) * HID + n] + xv.w * w[(k + 3) * HID + n];
        }
    }
    float dv = dinv[i];
    float4* go = (float4*)(g + (size_t)i * HID);
#pragma unroll
    for (int n4 = 0; n4 < 4; n4++) {
        float4 o;
        o.x = acc[n4 * 4 + 0] * dv;
        o.y = acc[n4 * 4 + 1] * dv;
        o.z = acc[n4 * 4 + 2] * dv;
        o.w = acc[n4 * 4 + 3] * dv;
        go[n4] = o;
    }
}

// ---------------- gather-sum + finish: h = [relu](dinv*(Σ g[src] + g[i]) + b) ----------------
// 4 threads per node, thread j owns float4 slice j.
__global__ __launch_bounds__(256) void k_gather(const float* __restrict__ g,
                                                const int* __restrict__ off,
                                                const int* __restrict__ ebuf,
                                                const float* __restrict__ dinv,
                                                const float* __restrict__ bias,
                                                float* __restrict__ h, int N, int do_relu) {
    int t = blockIdx.x * 256 + threadIdx.x;
    int i = t >> 2, j = t & 3;
    if (i >= N) return;
    int e0 = off[i], e1 = off[i + 1];
    float4 a = ((const float4*)(g + (size_t)i * HID))[j];  // self-loop term
    for (int e = e0; e < e1; e++) {
        int s = ebuf[e];
        float4 v = ((const float4*)(g + (size_t)s * HID))[j];
        a.x += v.x;
        a.y += v.y;
        a.z += v.z;
        a.w += v.w;
    }
    float dv = dinv[i];
    float4 bb = ((const float4*)bias)[j];
    float4 o;
    o.x = dv * a.x + bb.x;
    o.y = dv * a.y + bb.y;
    o.z = dv * a.z + bb.z;
    o.w = dv * a.w + bb.w;
    if (do_relu) {
        o.x = fmaxf(o.x, 0.f);
        o.y = fmaxf(o.y, 0.f);
        o.z = fmaxf(o.z, 0.f);
        o.w = fmaxf(o.w, 0.f);
    }
    ((float4*)(h + (size_t)i * HID))[j] = o;
}

// ---------------- GEMM2: g = (h1 @ W2) * dinv,  K=16 ----------------
__global__ __launch_bounds__(256) void k_gemm2(const float* __restrict__ h1,
                                               const float* __restrict__ W2,
                                               const float* __restrict__ dinv,
                                               float* __restrict__ g, int N) {
    __shared__ float w[HID * HID];
    if (threadIdx.x < HID * HID) w[threadIdx.x] = W2[threadIdx.x];
    __syncthreads();
    int i = blockIdx.x * 256 + threadIdx.x;
    if (i >= N) return;
    float hv[HID];
    const float4* hr = (const float4*)(h1 + (size_t)i * HID);
#pragma unroll
    for (int j = 0; j < 4; j++) {
        float4 v = hr[j];
        hv[j * 4 + 0] = v.x;
        hv[j * 4 + 1] = v.y;
        hv[j * 4 + 2] = v.z;
        hv[j * 4 + 3] = v.w;
    }
    float dv = dinv[i];
    float4* go = (float4*)(g + (size_t)i * HID);
#pragma unroll
    for (int n4 = 0; n4 < 4; n4++) {
        float4 o;
        float s0 = 0.f, s1 = 0.f, s2 = 0.f, s3 = 0.f;
#pragma unroll
        for (int k = 0; k < HID; k++) {
            s0 += hv[k] * w[k * HID + n4 * 4 + 0];
            s1 += hv[k] * w[k * HID + n4 * 4 + 1];
            s2 += hv[k] * w[k * HID + n4 * 4 + 2];
            s3 += hv[k] * w[k * HID + n4 * 4 + 3];
        }
        o.x = s0 * dv;
        o.y = s1 * dv;
        o.z = s2 * dv;
        o.w = s3 * dv;
        go[n4] = o;
    }
}

// ---------------- edge scoring ----------------
__global__ __launch_bounds__(256) void k_edge(const int* __restrict__ src,
                                              const int* __restrict__ dst,
                                              const float* __restrict__ h2,
                                              const float* __restrict__ Wf,
                                              const float* __restrict__ bf,
                                              float* __restrict__ pred, int E) {
    __shared__ float wf[33];
    if (threadIdx.x < 33) wf[threadIdx.x] = (threadIdx.x < 32) ? Wf[threadIdx.x] : bf[0];
    __syncthreads();
    int e = blockIdx.x * 256 + threadIdx.x;
    if (e >= E) return;
    int s = src[e], d = dst[e];
    const float4* hs = (const float4*)(h2 + (size_t)s * HID);
    const float4* hd = (const float4*)(h2 + (size_t)d * HID);
    float sum = wf[32];
#pragma unroll
    for (int j = 0; j < 4; j++) {
        float4 v = hs[j];
        sum += v.x * wf[j * 4 + 0] + v.y * wf[j * 4 + 1] + v.z * wf[j * 4 + 2] + v.w * wf[j * 4 + 3];
    }
#pragma unroll
    for (int j = 0; j < 4; j++) {
        float4 v = hd[j];
        sum += v.x * wf[16 + j * 4 + 0] + v.y * wf[16 + j * 4 + 1] + v.z * wf[16 + j * 4 + 2] +
               v.w * wf[16 + j * 4 + 3];
    }
    pred[e] = sum;
}

extern "C" void kernel_launch(void* const* d_in, const int* in_sizes, int n_in,
                              void* d_out, int out_size, void* d_ws, size_t ws_size,
                              hipStream_t stream) {
    const float* x  = (const float*)d_in[0];
    const int*   ei = (const int*)d_in[1];
    const float* W1 = (const float*)d_in[2];
    const float* b1 = (const float*)d_in[3];
    const float* W2 = (const float*)d_in[4];
    const float* b2 = (const float*)d_in[5];
    const float* Wf = (const float*)d_in[6];
    const float* bf = (const float*)d_in[7];
    float* pred = (float*)d_out;

    const int N = N_NODES, E = N_EDGES;
    const int* src = ei;
    const int* dst = ei + E;

    // workspace layout (bytes)
    char* w = (char*)d_ws;
    int*   deg    = (int*)(w + 0x0);        // 400000 B (reused as cursor)
    float* dinv   = (float*)(w + 0x80000);  // 400000 B
    int*   off    = (int*)(w + 0x100000);   // 400004 B
    int*   bsum   = (int*)(w + 0x180000);   // ~1.6 KB
    int*   ebuf   = (int*)(w + 0x200000);   // 12.8 MB
    float* g      = (float*)(w + 0xE40000); // 6.4 MB
    float* h      = (float*)(w + 0x1500000);// 6.4 MB (h1 then h2) -> total ~27.1 MB
    int* cursor = deg;                      // deg dead after scan1+dinv

    const int B = 256;
    int gE  = (E + B - 1) / B;      // 12500
    int gN  = (N + B - 1) / B;      // 391
    int gN4 = (4 * N + B - 1) / B;  // 1563
    int nb  = gN;                   // scan blocks

    // degree + dinv + CSR
    hipMemsetAsync(deg, 0, (size_t)N * 4, stream);
    k_deg<<<gE, B, 0, stream>>>(dst, deg, E);
    k_dinv<<<gN, B, 0, stream>>>(deg, dinv, N);
    k_scan1<<<gN, B, 0, stream>>>(deg, off, bsum, N);
    k_scan2<<<1, 512, 0, stream>>>(bsum, nb);
    k_scan3<<<gN, B, 0, stream>>>(off, bsum, cursor, N, E);
    k_fill<<<gE, B, 0, stream>>>(src, dst, cursor, ebuf, E);

    // conv1: g = (x@W1)*dinv ; h1 = relu(dinv*(gather+self)+b1)
    k_gemm1<<<gN, B, 0, stream>>>(x, W1, dinv, g, N);
    k_gather<<<gN4, B, 0, stream>>>(g, off, ebuf, dinv, b1, h, N, 1);

    // conv2: g = (h1@W2)*dinv ; h2 = dinv*(gather+self)+b2  (overwrites h)
    k_gemm2<<<gN, B, 0, stream>>>(h, W2, dinv, g, N);
    k_gather<<<gN4, B, 0, stream>>>(g, off, ebuf, dinv, b2, h, N, 0);

    // edge scoring
    k_edge<<<gE, B, 0, stream>>>(src, dst, h, Wf, bf, pred, E);
}